// Round 6
// baseline (226.872 us; speedup 1.0000x reference)
//
#include <hip/hip_runtime.h>
#include <hip/hip_bf16.h>

typedef __attribute__((ext_vector_type(8))) short short8;
typedef __attribute__((ext_vector_type(16))) float floatx16;

#define Bn 32
#define Ln 512
#define Cn 300
#define Hn 512
#define Nn (Bn*Ln)          // 16384
#define XBP 518             // 512 + 3 halo each side
#define XBC 320             // channels padded to 10*32
#define HK 1216             // 1200 padded to 19*64
#define LDSTC 72            // LDS row stride in shorts (conflict-free b128, verified r2/r3)

#define XROWS 134
#define XSZ (XROWS*LDSTC)   // 9648 shorts = 19296 B (x2 = 38.6 KB)
#define HSROWS 128
#define HSSZ (HSROWS*LDSTC) // 9216 shorts (x2 = 36.9 KB)

// workspace layout in bf16 elements
#define XB_ELEMS (Bn*XBP*XBC)            // 5,304,320
#define WB_ELEMS 1597440                  // (1+2+3+7)*122880, frag-major
#define WC_ELEMS (Hn*HK)                  // 622,592
#define XB_OFF 0
#define WB_OFF (XB_OFF + XB_ELEMS)
#define WC_OFF (WB_OFF + WB_ELEMS)
#define HB_OFF (WC_OFF + WC_ELEMS)

__device__ __forceinline__ float fast_tanh(float x) {
    float ax = __builtin_fabsf(x);
    float t  = __expf(-2.f * ax);
    float r  = __builtin_fmaf(-2.f * t, __frcp_rn(1.f + t), 1.f);  // (1-t)/(1+t)
    return __builtin_copysignf(r, x);
}

__device__ __forceinline__ short f2bf(float v) {
    __hip_bfloat16 h = __float2bfloat16(v);
    return *reinterpret_cast<short*>(&h);
}

// ---------------- merged prep kernel (8 elems/thread, short8 stores) ----------------
// Worth ~13us vs the scalar version (r5 residual 109us vs r0 residual 122.5us).
__global__ void prep_all(const float* __restrict__ x,
                         const float* __restrict__ w1, const float* __restrict__ w2,
                         const float* __restrict__ w3, const float* __restrict__ w7,
                         const float* __restrict__ slp_w,
                         __hip_bfloat16* __restrict__ wsb) {
    int g = blockIdx.x * 256 + threadIdx.x;
    int idx = g * 8;
    short8 o;
    if (idx < XB_ELEMS) {
        int c8 = idx % XBC;              // multiple of 8, XBC%8==0 so row-uniform
        int t  = idx / XBC;
        int p = t % XBP;
        int b = t / XBP;
        int l = p - 3;
        l = l < 0 ? 0 : (l > Ln - 1 ? Ln - 1 : l);   // replication pad
        const float* row = x + (b * Ln + l) * Cn;
        if (c8 + 8 <= Cn) {
            float4 a = *(const float4*)(row + c8);
            float4 bq = *(const float4*)(row + c8 + 4);
            o[0] = f2bf(a.x); o[1] = f2bf(a.y); o[2] = f2bf(a.z); o[3] = f2bf(a.w);
            o[4] = f2bf(bq.x); o[5] = f2bf(bq.y); o[6] = f2bf(bq.z); o[7] = f2bf(bq.w);
        } else {
#pragma unroll
            for (int e = 0; e < 8; ++e) {
                int c = c8 + e;
                o[e] = f2bf(c < Cn ? row[c] : 0.f);
            }
        }
        *(short8*)&wsb[idx] = o;
    } else if (idx < WB_OFF + WB_ELEMS) {
        int r = idx - WB_OFF, taps; const float* w;
        if (r < 122880)       { taps = 1; w = w1; }
        else if (r < 368640)  { taps = 2; w = w2; r -= 122880; }
        else if (r < 737280)  { taps = 3; w = w3; r -= 368640; }
        else                  { taps = 7; w = w7; r -= 737280; }
        int lane = (r >> 3) & 63;
        int f    = (r >> 9) & 15;
        int rt   = r >> 13;              // (mt*5+ch)*taps + t
        int t    = rt % taps;
        int mc   = rt / taps;
        int ch   = mc % 5;
        int mt   = mc / 5;
        int ks = f >> 2, mq = f & 3;
        int m = mt * 128 + mq * 32 + (lane & 31);
        int cb = ch * 64 + ks * 16 + (lane >> 5) * 8;
#pragma unroll
        for (int e = 0; e < 8; ++e) {
            int c = cb + e;
            o[e] = f2bf((m < Cn && c < Cn) ? w[(m * Cn + c) * taps + t] : 0.f);
        }
        *(short8*)&wsb[idx] = o;
    } else if (idx < WC_OFF + WC_ELEMS) {
        int r = idx - WC_OFF;
        int lane = (r >> 3) & 63;
        int f    = (r >> 9) & 15;
        int mc   = r >> 13;
        int ch   = mc % 19;
        int mt4  = mc / 19;
        int ks = f >> 2, mq = f & 3;
        int h = mt4 * 128 + mq * 32 + (lane & 31);
        int kb = ch * 64 + ks * 16 + (lane >> 5) * 8;
        const float* row = slp_w + h * 1500;
#pragma unroll
        for (int e = 0; e < 8; ++e) {
            int k = kb + e;
            float v;
            if (k < 600)       v = row[k];
            else if (k < 900)  v = row[k] + row[k + 300];
            else if (k < 1200) v = row[k + 300];
            else               v = 0.f;
            o[e] = f2bf(v);
        }
        *(short8*)&wsb[idx] = o;
    }
}

#define MFMA __builtin_amdgcn_mfma_f32_32x32x16_bf16

// ---------------- conv GEMM body (round-0 proven, verbatim — NO setprio) ----------------
// block tile 128n x 128m, 4 waves, wave tile 64n x 64m (acc 2x2 = 64 AGPR)
// B-frags direct from global, register double-buffered one stage ahead.
// x double-buffered in LDS; staging loads issued at stage TAPS-2 so they sit
// BEHIND all b-frags consumed this chunk in the vmcnt queue.
// Ledger of falsified variants (do NOT retry):
//  r1: __launch_bounds__(256,3)      -> spill, +16us conv
//  r2: 256-m wide tile (acc 2x4)     -> spill at 256-reg cap, +24us conv
//  r3: uniform-cost job pairing      -> residency-round loss, +9us conv
//  r5: s_setprio(1) around MFMA      -> priority-inverts barrier-coupled
//      staging waves, 68->113us conv (MfmaUtil 31->18%)
template<int TAPS, int LEAD>
__device__ __forceinline__ void conv_body(
        const short* __restrict__ xbs, const short* __restrict__ wsp,
        const float* __restrict__ bias, int cid, int mt, int nt,
        __hip_bfloat16* __restrict__ hbuf, short* xs) {
    const int tid  = threadIdx.x;
    const int lane = tid & 63;
    const int wave = tid >> 6;
    const int wn = wave & 1, wm = wave >> 1;
    const int lr = lane & 31;
    const int lk = (lane >> 5) << 3;
    const int TRIG = (TAPS >= 3) ? TAPS - 2 : 0;

    floatx16 acc[2][2];
#pragma unroll
    for (int i = 0; i < 2; i++)
#pragma unroll
        for (int j = 0; j < 2; j++)
#pragma unroll
            for (int r = 0; r < 16; r++) acc[i][j][r] = 0.f;

    short8 bA[8], bB[8], st[5];

    // prologue: stage chunk 0 + preload stage(0,0) b-frags
#pragma unroll
    for (int i = 0; i < 5; ++i) {
        int j = tid + 256 * i;
        if (i < 4 || j < 1072)
            st[i] = *(const short8*)&xbs[(j >> 3) * XBC + ((j & 7) << 3)];
    }
#pragma unroll
    for (int ks = 0; ks < 4; ++ks)
#pragma unroll
        for (int mf = 0; mf < 2; ++mf)
            bA[ks * 2 + mf] = *(const short8*)&wsp[(ks * 4 + wm * 2 + mf) * 512 + lane * 8];
#pragma unroll
    for (int i = 0; i < 5; ++i) {
        int j = tid + 256 * i;
        if (i < 4 || j < 1072)
            *(short8*)&xs[(j >> 3) * LDSTC + ((j & 7) << 3)] = st[i];
    }
    __syncthreads();

    for (int c5 = 0; c5 < 5; ++c5) {
        const short* cur = xs + (c5 & 1) * XSZ;
        short* nxt = xs + ((c5 + 1) & 1) * XSZ;
        const int c0n = (c5 + 1) * 64;
#pragma unroll
        for (int t = 0; t < TAPS; ++t) {
            // prefetch next stage's B fragments (older than any staging issued later)
            if (!(c5 == 4 && t == TAPS - 1)) {
                const short* wtn = (t + 1 < TAPS) ? wsp + (c5 * TAPS + t + 1) * 8192
                                                  : wsp + ((c5 + 1) * TAPS) * 8192;
#pragma unroll
                for (int ks = 0; ks < 4; ++ks)
#pragma unroll
                    for (int mf = 0; mf < 2; ++mf)
                        bB[ks * 2 + mf] = *(const short8*)&wtn[(ks * 4 + wm * 2 + mf) * 512 + lane * 8];
            }
            if (t == TRIG && c5 < 4) {           // staging: issued after this chunk's b-frags
#pragma unroll
                for (int i = 0; i < 5; ++i) {
                    int j = tid + 256 * i;
                    if (i < 4 || j < 1072)
                        st[i] = *(const short8*)&xbs[(j >> 3) * XBC + c0n + ((j & 7) << 3)];
                }
            }
            const int sh = t - LEAD + 3;
            const int ar = (wn * 64 + lr + sh) * LDSTC + lk;
#pragma unroll
            for (int ks = 0; ks < 4; ++ks) {
                short8 a0 = *(const short8*)&cur[ar + ks * 16];
                short8 a1 = *(const short8*)&cur[ar + 32 * LDSTC + ks * 16];
                acc[0][0] = MFMA(a0, bA[ks * 2 + 0], acc[0][0], 0, 0, 0);
                acc[0][1] = MFMA(a0, bA[ks * 2 + 1], acc[0][1], 0, 0, 0);
                acc[1][0] = MFMA(a1, bA[ks * 2 + 0], acc[1][0], 0, 0, 0);
                acc[1][1] = MFMA(a1, bA[ks * 2 + 1], acc[1][1], 0, 0, 0);
            }
            if (!(c5 == 4 && t == TAPS - 1)) {
#pragma unroll
                for (int f = 0; f < 8; ++f) bA[f] = bB[f];
            }
        }
        if (c5 < 4) {
#pragma unroll
            for (int i = 0; i < 5; ++i) {
                int j = tid + 256 * i;
                if (i < 4 || j < 1072)
                    *(short8*)&nxt[(j >> 3) * LDSTC + ((j & 7) << 3)] = st[i];
            }
        }
        __syncthreads();
    }

#pragma unroll
    for (int mi = 0; mi < 2; ++mi) {
        int mloc = mt * 128 + wm * 64 + mi * 32 + lr;
        int col = cid * Cn + mloc;
        if (mloc < Cn) {
            float bv = bias[mloc];
#pragma unroll
            for (int ni = 0; ni < 2; ++ni) {
                floatx16 v = acc[ni][mi];
#pragma unroll
                for (int reg = 0; reg < 16; ++reg) {
                    int nl = wn * 64 + ni * 32 + (reg & 3) + ((reg >> 2) << 3) + ((lane >> 5) << 2);
                    int n = nt * 128 + nl;
                    hbuf[n * HK + col] = __float2bfloat16(fast_tanh(v[reg] + bv));
                }
            }
        } else if (cid == 3 && col < HK) {
            // zero-fill hbuf pad columns 1200..1215 (linear kernel MFMA reads them)
            __hip_bfloat16 z = __float2bfloat16(0.f);
#pragma unroll
            for (int ni = 0; ni < 2; ++ni)
#pragma unroll
                for (int reg = 0; reg < 16; ++reg) {
                    int nl = wn * 64 + ni * 32 + (reg & 3) + ((reg >> 2) << 3) + ((lane >> 5) << 2);
                    int n = nt * 128 + nl;
                    hbuf[n * HK + col] = z;
                }
        }
    }
}

// grid (128 n-tiles of 128, 12 y; heavy convs first) — round-0 proven config.
// Best measured conv: 67.5-68.8us (reproduced r0/r4; VGPR 96, FETCH ~21MB,
// WRITE ~48MB, MfmaUtil ~31%, 0 bank conflicts).
__global__ __launch_bounds__(256, 2) void conv_kernel(
        const __hip_bfloat16* __restrict__ xbg, const __hip_bfloat16* __restrict__ Wbg,
        const float* __restrict__ bias1, const float* __restrict__ bias2,
        const float* __restrict__ bias3, const float* __restrict__ bias7,
        __hip_bfloat16* __restrict__ hbuf) {
    __shared__ __align__(16) short xs[2 * XSZ];

    const int nt = blockIdx.x;
    const int my = blockIdx.y;
    const int g  = my / 3;                   // 0:conv7 1:conv3 2:conv2 3:conv1
    const int mt = my % 3;

    const int b  = nt >> 2;
    const int l0 = (nt & 3) << 7;
    const short* xbs = (const short*)xbg + (b * XBP + l0) * XBC;
    const short* wb  = (const short*)Wbg;

    if (g == 0)      conv_body<7, 3>(xbs, wb + 737280 + mt * 7 * 40960, bias7, 3, mt, nt, hbuf, xs);
    else if (g == 1) conv_body<3, 1>(xbs, wb + 368640 + mt * 3 * 40960, bias3, 2, mt, nt, hbuf, xs);
    else if (g == 2) conv_body<2, 0>(xbs, wb + 122880 + mt * 2 * 40960, bias2, 1, mt, nt, hbuf, xs);
    else             conv_body<1, 0>(xbs, wb +      0 + mt * 1 * 40960, bias1, 0, mt, nt, hbuf, xs);
}

// ---------------- linear GEMM (round-0 LDS version, proven) ----------------
// r4 measured the barrier-free direct-global variant at +41us vs this: the
// one-chunk-ahead LDS pipeline + single barrier/chunk hides L2 latency better
// than free-running waves at ~2 waves/SIMD. Keep this version.
__global__ __launch_bounds__(256, 2) void linear_kernel(
        const __hip_bfloat16* __restrict__ hbufg, const __hip_bfloat16* __restrict__ Wcg,
        const float* __restrict__ slp_b, float* __restrict__ out) {
    __shared__ __align__(16) short hs[2 * HSSZ];

    const int tid  = threadIdx.x;
    const int lane = tid & 63;
    const int wave = tid >> 6;
    const int wn = wave & 1, wm = wave >> 1;
    const int lr = lane & 31;
    const int lk = (lane >> 5) << 3;

    const int nt  = blockIdx.x;
    const int mt4 = blockIdx.y;

    const short* hbp = (const short*)hbufg + nt * 128 * HK;
    const short* wcp = (const short*)Wcg + mt4 * 155648;   // 19*16*512

    floatx16 acc[2][2];
#pragma unroll
    for (int i = 0; i < 2; i++)
#pragma unroll
        for (int j = 0; j < 2; j++)
#pragma unroll
            for (int r = 0; r < 16; r++) acc[i][j][r] = 0.f;

    short8 bA[8], bB[8], st[4];

#pragma unroll
    for (int i = 0; i < 4; ++i) {
        int j = tid + 256 * i;
        st[i] = *(const short8*)&hbp[(j >> 3) * HK + ((j & 7) << 3)];
    }
#pragma unroll
    for (int ks = 0; ks < 4; ++ks)
#pragma unroll
        for (int mf = 0; mf < 2; ++mf)
            bA[ks * 2 + mf] = *(const short8*)&wcp[(ks * 4 + wm * 2 + mf) * 512 + lane * 8];
#pragma unroll
    for (int i = 0; i < 4; ++i) {
        int j = tid + 256 * i;
        *(short8*)&hs[(j >> 3) * LDSTC + ((j & 7) << 3)] = st[i];
    }
    __syncthreads();

    for (int ch = 0; ch < 19; ++ch) {
        const short* cur = hs + (ch & 1) * HSSZ;
        short* nxt = hs + ((ch + 1) & 1) * HSSZ;
        if (ch < 18) {
            const short* wtn = wcp + (ch + 1) * 8192;
#pragma unroll
            for (int ks = 0; ks < 4; ++ks)
#pragma unroll
                for (int mf = 0; mf < 2; ++mf)
                    bB[ks * 2 + mf] = *(const short8*)&wtn[(ks * 4 + wm * 2 + mf) * 512 + lane * 8];
            const int c0n = (ch + 1) * 64;
#pragma unroll
            for (int i = 0; i < 4; ++i) {
                int j = tid + 256 * i;
                st[i] = *(const short8*)&hbp[(j >> 3) * HK + c0n + ((j & 7) << 3)];
            }
        }
        const int ar = (wn * 64 + lr) * LDSTC + lk;
#pragma unroll
        for (int ks = 0; ks < 4; ++ks) {
            short8 a0 = *(const short8*)&cur[ar + ks * 16];
            short8 a1 = *(const short8*)&cur[ar + 32 * LDSTC + ks * 16];
            acc[0][0] = MFMA(a0, bA[ks * 2 + 0], acc[0][0], 0, 0, 0);
            acc[0][1] = MFMA(a0, bA[ks * 2 + 1], acc[0][1], 0, 0, 0);
            acc[1][0] = MFMA(a1, bA[ks * 2 + 0], acc[1][0], 0, 0, 0);
            acc[1][1] = MFMA(a1, bA[ks * 2 + 1], acc[1][1], 0, 0, 0);
        }
        if (ch < 18) {
#pragma unroll
            for (int f = 0; f < 8; ++f) bA[f] = bB[f];
#pragma unroll
            for (int i = 0; i < 4; ++i) {
                int j = tid + 256 * i;
                *(short8*)&nxt[(j >> 3) * LDSTC + ((j & 7) << 3)] = st[i];
            }
        }
        __syncthreads();
    }

#pragma unroll
    for (int mi = 0; mi < 2; ++mi) {
        int h = mt4 * 128 + wm * 64 + mi * 32 + lr;
        float bv = slp_b[h];
#pragma unroll
        for (int ni = 0; ni < 2; ++ni) {
            floatx16 v = acc[ni][mi];
#pragma unroll
            for (int reg = 0; reg < 16; ++reg) {
                int nl = wn * 64 + ni * 32 + (reg & 3) + ((reg >> 2) << 3) + ((lane >> 5) << 2);
                int n = nt * 128 + nl;
                out[n * Hn + h] = fast_tanh(v[reg] + bv);
            }
        }
    }
}

// ---------------- launch ----------------

extern "C" void kernel_launch(void* const* d_in, const int* in_sizes, int n_in,
                              void* d_out, int out_size, void* d_ws, size_t ws_size,
                              hipStream_t stream) {
    const float* x     = (const float*)d_in[0];
    const float* w1    = (const float*)d_in[1];
    const float* b1    = (const float*)d_in[2];
    const float* w2    = (const float*)d_in[3];
    const float* b2    = (const float*)d_in[4];
    const float* w3    = (const float*)d_in[5];
    const float* b3    = (const float*)d_in[6];
    const float* w7    = (const float*)d_in[7];
    const float* b7    = (const float*)d_in[8];
    const float* slp_w = (const float*)d_in[9];
    const float* slp_b = (const float*)d_in[10];

    __hip_bfloat16* wsb = (__hip_bfloat16*)d_ws;

    const int prep_groups = (XB_ELEMS + WB_ELEMS + WC_ELEMS) / 8;   // 940,544
    prep_all<<<(prep_groups + 255) / 256, 256, 0, stream>>>(x, w1, w2, w3, w7, slp_w, wsb);

    conv_kernel<<<dim3(128, 12), 256, 0, stream>>>(wsb + XB_OFF, wsb + WB_OFF,
                                                   b1, b2, b3, b7, wsb + HB_OFF);
    linear_kernel<<<dim3(128, 4), 256, 0, stream>>>(wsb + HB_OFF, wsb + WC_OFF,
                                                    slp_b, (float*)d_out);
}

// Round 7
// 191.583 us; speedup vs baseline: 1.1842x; 1.1842x over previous
//
#include <hip/hip_runtime.h>
#include <hip/hip_bf16.h>

// ============================================================================
// ROUND 7 = REPEAT SAMPLE of the champion config (byte-identical to round 6).
// Rationale: conv body identical to r4 measured 67.9us (r4) vs 124.4us (r6)
// with identical VGPR/LDS/conflict counters and 1.63x lower hbm_gbps on the
// same byte counts -> environmental (clock/container) variance, not code.
// This round establishes the noise band before any further structural change.
// ============================================================================

typedef __attribute__((ext_vector_type(8))) short short8;
typedef __attribute__((ext_vector_type(16))) float floatx16;

#define Bn 32
#define Ln 512
#define Cn 300
#define Hn 512
#define Nn (Bn*Ln)          // 16384
#define XBP 518             // 512 + 3 halo each side
#define XBC 320             // channels padded to 10*32
#define HK 1216             // 1200 padded to 19*64
#define LDSTC 72            // LDS row stride in shorts (conflict-free b128, verified r2/r3)

#define XROWS 134
#define XSZ (XROWS*LDSTC)   // 9648 shorts = 19296 B (x2 = 38.6 KB)
#define HSROWS 128
#define HSSZ (HSROWS*LDSTC) // 9216 shorts (x2 = 36.9 KB)

// workspace layout in bf16 elements
#define XB_ELEMS (Bn*XBP*XBC)            // 5,304,320
#define WB_ELEMS 1597440                  // (1+2+3+7)*122880, frag-major
#define WC_ELEMS (Hn*HK)                  // 622,592
#define XB_OFF 0
#define WB_OFF (XB_OFF + XB_ELEMS)
#define WC_OFF (WB_OFF + WB_ELEMS)
#define HB_OFF (WC_OFF + WC_ELEMS)

__device__ __forceinline__ float fast_tanh(float x) {
    float ax = __builtin_fabsf(x);
    float t  = __expf(-2.f * ax);
    float r  = __builtin_fmaf(-2.f * t, __frcp_rn(1.f + t), 1.f);  // (1-t)/(1+t)
    return __builtin_copysignf(r, x);
}

__device__ __forceinline__ short f2bf(float v) {
    __hip_bfloat16 h = __float2bfloat16(v);
    return *reinterpret_cast<short*>(&h);
}

// ---------------- merged prep kernel (8 elems/thread, short8 stores) ----------------
__global__ void prep_all(const float* __restrict__ x,
                         const float* __restrict__ w1, const float* __restrict__ w2,
                         const float* __restrict__ w3, const float* __restrict__ w7,
                         const float* __restrict__ slp_w,
                         __hip_bfloat16* __restrict__ wsb) {
    int g = blockIdx.x * 256 + threadIdx.x;
    int idx = g * 8;
    short8 o;
    if (idx < XB_ELEMS) {
        int c8 = idx % XBC;              // multiple of 8, XBC%8==0 so row-uniform
        int t  = idx / XBC;
        int p = t % XBP;
        int b = t / XBP;
        int l = p - 3;
        l = l < 0 ? 0 : (l > Ln - 1 ? Ln - 1 : l);   // replication pad
        const float* row = x + (b * Ln + l) * Cn;
        if (c8 + 8 <= Cn) {
            float4 a = *(const float4*)(row + c8);
            float4 bq = *(const float4*)(row + c8 + 4);
            o[0] = f2bf(a.x); o[1] = f2bf(a.y); o[2] = f2bf(a.z); o[3] = f2bf(a.w);
            o[4] = f2bf(bq.x); o[5] = f2bf(bq.y); o[6] = f2bf(bq.z); o[7] = f2bf(bq.w);
        } else {
#pragma unroll
            for (int e = 0; e < 8; ++e) {
                int c = c8 + e;
                o[e] = f2bf(c < Cn ? row[c] : 0.f);
            }
        }
        *(short8*)&wsb[idx] = o;
    } else if (idx < WB_OFF + WB_ELEMS) {
        int r = idx - WB_OFF, taps; const float* w;
        if (r < 122880)       { taps = 1; w = w1; }
        else if (r < 368640)  { taps = 2; w = w2; r -= 122880; }
        else if (r < 737280)  { taps = 3; w = w3; r -= 368640; }
        else                  { taps = 7; w = w7; r -= 737280; }
        int lane = (r >> 3) & 63;
        int f    = (r >> 9) & 15;
        int rt   = r >> 13;              // (mt*5+ch)*taps + t
        int t    = rt % taps;
        int mc   = rt / taps;
        int ch   = mc % 5;
        int mt   = mc / 5;
        int ks = f >> 2, mq = f & 3;
        int m = mt * 128 + mq * 32 + (lane & 31);
        int cb = ch * 64 + ks * 16 + (lane >> 5) * 8;
#pragma unroll
        for (int e = 0; e < 8; ++e) {
            int c = cb + e;
            o[e] = f2bf((m < Cn && c < Cn) ? w[(m * Cn + c) * taps + t] : 0.f);
        }
        *(short8*)&wsb[idx] = o;
    } else if (idx < WC_OFF + WC_ELEMS) {
        int r = idx - WC_OFF;
        int lane = (r >> 3) & 63;
        int f    = (r >> 9) & 15;
        int mc   = r >> 13;
        int ch   = mc % 19;
        int mt4  = mc / 19;
        int ks = f >> 2, mq = f & 3;
        int h = mt4 * 128 + mq * 32 + (lane & 31);
        int kb = ch * 64 + ks * 16 + (lane >> 5) * 8;
        const float* row = slp_w + h * 1500;
#pragma unroll
        for (int e = 0; e < 8; ++e) {
            int k = kb + e;
            float v;
            if (k < 600)       v = row[k];
            else if (k < 900)  v = row[k] + row[k + 300];
            else if (k < 1200) v = row[k + 300];
            else               v = 0.f;
            o[e] = f2bf(v);
        }
        *(short8*)&wsb[idx] = o;
    }
}

#define MFMA __builtin_amdgcn_mfma_f32_32x32x16_bf16

// ---------------- conv GEMM body (round-0 proven, verbatim) ----------------
// block tile 128n x 128m, 4 waves, wave tile 64n x 64m (acc 2x2 = 64 AGPR)
// B-frags direct from global, register double-buffered one stage ahead.
// x double-buffered in LDS; staging loads issued at stage TAPS-2 so they sit
// BEHIND all b-frags consumed this chunk in the vmcnt queue.
// Ledger of falsified variants (do NOT retry):
//  r1: __launch_bounds__(256,3)      -> spill (counter-proven: scratch traffic)
//  r2: 256-m wide tile (acc 2x4)     -> spill at 256-reg cap (counter-proven)
//  r3: uniform-cost job pairing      -> residency-round loss
//  r5: s_setprio(1) around MFMA      -> regressed (magnitude env-confounded)
//  r6: (repeat of this exact body)   -> 124us on a 1.8x-slow machine; proves
//      cross-round environmental noise ~±20-80%, counters-per-byte identical
template<int TAPS, int LEAD>
__device__ __forceinline__ void conv_body(
        const short* __restrict__ xbs, const short* __restrict__ wsp,
        const float* __restrict__ bias, int cid, int mt, int nt,
        __hip_bfloat16* __restrict__ hbuf, short* xs) {
    const int tid  = threadIdx.x;
    const int lane = tid & 63;
    const int wave = tid >> 6;
    const int wn = wave & 1, wm = wave >> 1;
    const int lr = lane & 31;
    const int lk = (lane >> 5) << 3;
    const int TRIG = (TAPS >= 3) ? TAPS - 2 : 0;

    floatx16 acc[2][2];
#pragma unroll
    for (int i = 0; i < 2; i++)
#pragma unroll
        for (int j = 0; j < 2; j++)
#pragma unroll
            for (int r = 0; r < 16; r++) acc[i][j][r] = 0.f;

    short8 bA[8], bB[8], st[5];

    // prologue: stage chunk 0 + preload stage(0,0) b-frags
#pragma unroll
    for (int i = 0; i < 5; ++i) {
        int j = tid + 256 * i;
        if (i < 4 || j < 1072)
            st[i] = *(const short8*)&xbs[(j >> 3) * XBC + ((j & 7) << 3)];
    }
#pragma unroll
    for (int ks = 0; ks < 4; ++ks)
#pragma unroll
        for (int mf = 0; mf < 2; ++mf)
            bA[ks * 2 + mf] = *(const short8*)&wsp[(ks * 4 + wm * 2 + mf) * 512 + lane * 8];
#pragma unroll
    for (int i = 0; i < 5; ++i) {
        int j = tid + 256 * i;
        if (i < 4 || j < 1072)
            *(short8*)&xs[(j >> 3) * LDSTC + ((j & 7) << 3)] = st[i];
    }
    __syncthreads();

    for (int c5 = 0; c5 < 5; ++c5) {
        const short* cur = xs + (c5 & 1) * XSZ;
        short* nxt = xs + ((c5 + 1) & 1) * XSZ;
        const int c0n = (c5 + 1) * 64;
#pragma unroll
        for (int t = 0; t < TAPS; ++t) {
            // prefetch next stage's B fragments (older than any staging issued later)
            if (!(c5 == 4 && t == TAPS - 1)) {
                const short* wtn = (t + 1 < TAPS) ? wsp + (c5 * TAPS + t + 1) * 8192
                                                  : wsp + ((c5 + 1) * TAPS) * 8192;
#pragma unroll
                for (int ks = 0; ks < 4; ++ks)
#pragma unroll
                    for (int mf = 0; mf < 2; ++mf)
                        bB[ks * 2 + mf] = *(const short8*)&wtn[(ks * 4 + wm * 2 + mf) * 512 + lane * 8];
            }
            if (t == TRIG && c5 < 4) {           // staging: issued after this chunk's b-frags
#pragma unroll
                for (int i = 0; i < 5; ++i) {
                    int j = tid + 256 * i;
                    if (i < 4 || j < 1072)
                        st[i] = *(const short8*)&xbs[(j >> 3) * XBC + c0n + ((j & 7) << 3)];
                }
            }
            const int sh = t - LEAD + 3;
            const int ar = (wn * 64 + lr + sh) * LDSTC + lk;
#pragma unroll
            for (int ks = 0; ks < 4; ++ks) {
                short8 a0 = *(const short8*)&cur[ar + ks * 16];
                short8 a1 = *(const short8*)&cur[ar + 32 * LDSTC + ks * 16];
                acc[0][0] = MFMA(a0, bA[ks * 2 + 0], acc[0][0], 0, 0, 0);
                acc[0][1] = MFMA(a0, bA[ks * 2 + 1], acc[0][1], 0, 0, 0);
                acc[1][0] = MFMA(a1, bA[ks * 2 + 0], acc[1][0], 0, 0, 0);
                acc[1][1] = MFMA(a1, bA[ks * 2 + 1], acc[1][1], 0, 0, 0);
            }
            if (!(c5 == 4 && t == TAPS - 1)) {
#pragma unroll
                for (int f = 0; f < 8; ++f) bA[f] = bB[f];
            }
        }
        if (c5 < 4) {
#pragma unroll
            for (int i = 0; i < 5; ++i) {
                int j = tid + 256 * i;
                if (i < 4 || j < 1072)
                    *(short8*)&nxt[(j >> 3) * LDSTC + ((j & 7) << 3)] = st[i];
            }
        }
        __syncthreads();
    }

#pragma unroll
    for (int mi = 0; mi < 2; ++mi) {
        int mloc = mt * 128 + wm * 64 + mi * 32 + lr;
        int col = cid * Cn + mloc;
        if (mloc < Cn) {
            float bv = bias[mloc];
#pragma unroll
            for (int ni = 0; ni < 2; ++ni) {
                floatx16 v = acc[ni][mi];
#pragma unroll
                for (int reg = 0; reg < 16; ++reg) {
                    int nl = wn * 64 + ni * 32 + (reg & 3) + ((reg >> 2) << 3) + ((lane >> 5) << 2);
                    int n = nt * 128 + nl;
                    hbuf[n * HK + col] = __float2bfloat16(fast_tanh(v[reg] + bv));
                }
            }
        } else if (cid == 3 && col < HK) {
            // zero-fill hbuf pad columns 1200..1215 (linear kernel MFMA reads them)
            __hip_bfloat16 z = __float2bfloat16(0.f);
#pragma unroll
            for (int ni = 0; ni < 2; ++ni)
#pragma unroll
                for (int reg = 0; reg < 16; ++reg) {
                    int nl = wn * 64 + ni * 32 + (reg & 3) + ((reg >> 2) << 3) + ((lane >> 5) << 2);
                    int n = nt * 128 + nl;
                    hbuf[n * HK + col] = z;
                }
        }
    }
}

// grid (128 n-tiles of 128, 12 y; heavy convs first) — round-0 proven config.
// Best measured conv: 67.5-68.8us (r0/r4; VGPR 96, FETCH ~21MB, WRITE ~48MB,
// MfmaUtil ~31%, 0 bank conflicts, hbm_gbps ~1030-1065 on fast machines).
__global__ __launch_bounds__(256, 2) void conv_kernel(
        const __hip_bfloat16* __restrict__ xbg, const __hip_bfloat16* __restrict__ Wbg,
        const float* __restrict__ bias1, const float* __restrict__ bias2,
        const float* __restrict__ bias3, const float* __restrict__ bias7,
        __hip_bfloat16* __restrict__ hbuf) {
    __shared__ __align__(16) short xs[2 * XSZ];

    const int nt = blockIdx.x;
    const int my = blockIdx.y;
    const int g  = my / 3;                   // 0:conv7 1:conv3 2:conv2 3:conv1
    const int mt = my % 3;

    const int b  = nt >> 2;
    const int l0 = (nt & 3) << 7;
    const short* xbs = (const short*)xbg + (b * XBP + l0) * XBC;
    const short* wb  = (const short*)Wbg;

    if (g == 0)      conv_body<7, 3>(xbs, wb + 737280 + mt * 7 * 40960, bias7, 3, mt, nt, hbuf, xs);
    else if (g == 1) conv_body<3, 1>(xbs, wb + 368640 + mt * 3 * 40960, bias3, 2, mt, nt, hbuf, xs);
    else if (g == 2) conv_body<2, 0>(xbs, wb + 122880 + mt * 2 * 40960, bias2, 1, mt, nt, hbuf, xs);
    else             conv_body<1, 0>(xbs, wb +      0 + mt * 1 * 40960, bias1, 0, mt, nt, hbuf, xs);
}

// ---------------- linear GEMM (round-0 LDS version, proven) ----------------
// r4 measured the barrier-free direct-global variant as a regression vs this:
// the one-chunk-ahead LDS pipeline + single barrier/chunk hides L2 latency
// better than free-running waves at ~2 waves/SIMD. Keep this version.
__global__ __launch_bounds__(256, 2) void linear_kernel(
        const __hip_bfloat16* __restrict__ hbufg, const __hip_bfloat16* __restrict__ Wcg,
        const float* __restrict__ slp_b, float* __restrict__ out) {
    __shared__ __align__(16) short hs[2 * HSSZ];

    const int tid  = threadIdx.x;
    const int lane = tid & 63;
    const int wave = tid >> 6;
    const int wn = wave & 1, wm = wave >> 1;
    const int lr = lane & 31;
    const int lk = (lane >> 5) << 3;

    const int nt  = blockIdx.x;
    const int mt4 = blockIdx.y;

    const short* hbp = (const short*)hbufg + nt * 128 * HK;
    const short* wcp = (const short*)Wcg + mt4 * 155648;   // 19*16*512

    floatx16 acc[2][2];
#pragma unroll
    for (int i = 0; i < 2; i++)
#pragma unroll
        for (int j = 0; j < 2; j++)
#pragma unroll
            for (int r = 0; r < 16; r++) acc[i][j][r] = 0.f;

    short8 bA[8], bB[8], st[4];

#pragma unroll
    for (int i = 0; i < 4; ++i) {
        int j = tid + 256 * i;
        st[i] = *(const short8*)&hbp[(j >> 3) * HK + ((j & 7) << 3)];
    }
#pragma unroll
    for (int ks = 0; ks < 4; ++ks)
#pragma unroll
        for (int mf = 0; mf < 2; ++mf)
            bA[ks * 2 + mf] = *(const short8*)&wcp[(ks * 4 + wm * 2 + mf) * 512 + lane * 8];
#pragma unroll
    for (int i = 0; i < 4; ++i) {
        int j = tid + 256 * i;
        *(short8*)&hs[(j >> 3) * LDSTC + ((j & 7) << 3)] = st[i];
    }
    __syncthreads();

    for (int ch = 0; ch < 19; ++ch) {
        const short* cur = hs + (ch & 1) * HSSZ;
        short* nxt = hs + ((ch + 1) & 1) * HSSZ;
        if (ch < 18) {
            const short* wtn = wcp + (ch + 1) * 8192;
#pragma unroll
            for (int ks = 0; ks < 4; ++ks)
#pragma unroll
                for (int mf = 0; mf < 2; ++mf)
                    bB[ks * 2 + mf] = *(const short8*)&wtn[(ks * 4 + wm * 2 + mf) * 512 + lane * 8];
            const int c0n = (ch + 1) * 64;
#pragma unroll
            for (int i = 0; i < 4; ++i) {
                int j = tid + 256 * i;
                st[i] = *(const short8*)&hbp[(j >> 3) * HK + c0n + ((j & 7) << 3)];
            }
        }
        const int ar = (wn * 64 + lr) * LDSTC + lk;
#pragma unroll
        for (int ks = 0; ks < 4; ++ks) {
            short8 a0 = *(const short8*)&cur[ar + ks * 16];
            short8 a1 = *(const short8*)&cur[ar + 32 * LDSTC + ks * 16];
            acc[0][0] = MFMA(a0, bA[ks * 2 + 0], acc[0][0], 0, 0, 0);
            acc[0][1] = MFMA(a0, bA[ks * 2 + 1], acc[0][1], 0, 0, 0);
            acc[1][0] = MFMA(a1, bA[ks * 2 + 0], acc[1][0], 0, 0, 0);
            acc[1][1] = MFMA(a1, bA[ks * 2 + 1], acc[1][1], 0, 0, 0);
        }
        if (ch < 18) {
#pragma unroll
            for (int f = 0; f < 8; ++f) bA[f] = bB[f];
#pragma unroll
            for (int i = 0; i < 4; ++i) {
                int j = tid + 256 * i;
                *(short8*)&nxt[(j >> 3) * LDSTC + ((j & 7) << 3)] = st[i];
            }
        }
        __syncthreads();
    }

#pragma unroll
    for (int mi = 0; mi < 2; ++mi) {
        int h = mt4 * 128 + wm * 64 + mi * 32 + lr;
        float bv = slp_b[h];
#pragma unroll
        for (int ni = 0; ni < 2; ++ni) {
            floatx16 v = acc[ni][mi];
#pragma unroll
            for (int reg = 0; reg < 16; ++reg) {
                int nl = wn * 64 + ni * 32 + (reg & 3) + ((reg >> 2) << 3) + ((lane >> 5) << 2);
                int n = nt * 128 + nl;
                out[n * Hn + h] = fast_tanh(v[reg] + bv);
            }
        }
    }
}

// ---------------- launch ----------------

extern "C" void kernel_launch(void* const* d_in, const int* in_sizes, int n_in,
                              void* d_out, int out_size, void* d_ws, size_t ws_size,
                              hipStream_t stream) {
    const float* x     = (const float*)d_in[0];
    const float* w1    = (const float*)d_in[1];
    const float* b1    = (const float*)d_in[2];
    const float* w2    = (const float*)d_in[3];
    const float* b2    = (const float*)d_in[4];
    const float* w3    = (const float*)d_in[5];
    const float* b3    = (const float*)d_in[6];
    const float* w7    = (const float*)d_in[7];
    const float* b7    = (const float*)d_in[8];
    const float* slp_w = (const float*)d_in[9];
    const float* slp_b = (const float*)d_in[10];

    __hip_bfloat16* wsb = (__hip_bfloat16*)d_ws;

    const int prep_groups = (XB_ELEMS + WB_ELEMS + WC_ELEMS) / 8;   // 940,544
    prep_all<<<(prep_groups + 255) / 256, 256, 0, stream>>>(x, w1, w2, w3, w7, slp_w, wsb);

    conv_kernel<<<dim3(128, 12), 256, 0, stream>>>(wsb + XB_OFF, wsb + WB_OFF,
                                                   b1, b2, b3, b7, wsb + HB_OFF);
    linear_kernel<<<dim3(128, 4), 256, 0, stream>>>(wsb + HB_OFF, wsb + WC_OFF,
                                                    slp_b, (float*)d_out);
}